// Round 3
// baseline (1197.917 us; speedup 1.0000x reference)
//
#include <hip/hip_runtime.h>

#define GI  1220          // g_i feature dim
#define KP  1280          // K padded to 40 * 32
#define BK  128           // K-chunk
#define NCH (KP / BK)     // 10 chunks
#define NP  192           // hidden dim padded 150 -> 192
#define ABW 320           // AB row: A[0:160) | B[160:320)

typedef __bf16        bf16x8 __attribute__((ext_vector_type(8)));
typedef float         f32x4  __attribute__((ext_vector_type(4)));
typedef unsigned int  u32x4  __attribute__((ext_vector_type(4)));

__device__ __forceinline__ unsigned short f2bf(float f) {
  __bf16 h = (__bf16)f;
  return __builtin_bit_cast(unsigned short, h);
}
__device__ __forceinline__ float bf2f(unsigned short u) {
  return (float)__builtin_bit_cast(__bf16, u);
}
__device__ __forceinline__ unsigned int pk2(float a, float b) {
  return (unsigned int)f2bf(a) | ((unsigned int)f2bf(b) << 16);
}
// packed bf16x2 product
__device__ __forceinline__ unsigned int mulbf2(unsigned int a, unsigned int b) {
  float xl = __builtin_bit_cast(float, a << 16);
  float xh = __builtin_bit_cast(float, a & 0xffff0000u);
  float yl = __builtin_bit_cast(float, b << 16);
  float yh = __builtin_bit_cast(float, b & 0xffff0000u);
  return pk2(xl * yl, xh * yh);
}

// ---------------------------------------------------------------------------
// prep: bf16 transposed weights + fp32 proj tables (b1 folded into dist rows)
// ---------------------------------------------------------------------------
__global__ void prep_kernel(const float* __restrict__ W1, const float* __restrict__ W2,
                            const float* __restrict__ b1,
                            const float* __restrict__ de, const float* __restrict__ ge,
                            const float* __restrict__ se,
                            unsigned short* __restrict__ W1ab_t,
                            unsigned short* __restrict__ W1c_t,
                            unsigned short* __restrict__ W2_t,
                            float* __restrict__ projs) {
  int idx = blockIdx.x * 256 + threadIdx.x;
  const int R1 = ABW * KP, R2 = NP * KP, R3 = NP * NP, R4 = 20 * NP;
  if (idx < R1) {
    int n = idx / KP, k = idx % KP;
    float v = 0.f;
    if (k < GI) {
      if (n < 150)                  v = W1[k * 150 + n];
      else if (n >= 160 && n < 310) v = W1[(GI + k) * 150 + (n - 160)];
    }
    W1ab_t[idx] = f2bf(v);
    return;
  }
  idx -= R1;
  if (idx < R2) {
    int n = idx / KP, k = idx % KP;
    float v = (k < GI && n < 150) ? W1[(2 * GI + k) * 150 + n] : 0.f;
    W1c_t[idx] = f2bf(v);
    return;
  }
  idx -= R2;
  if (idx < R3) {
    int n = idx / NP, k = idx % NP;
    float v = (n < 150 && k < 150) ? W2[k * 150 + n] : 0.f;
    W2_t[idx] = f2bf(v);
    return;
  }
  idx -= R3;
  if (idx < R4) {
    int r = idx / NP, n = idx % NP;
    float v = 0.f;
    if (n < 150) {
      if (r < 9) {
        v = b1[n];
        for (int t = 0; t < 20; ++t) v += de[r * 20 + t] * W1[(3660 + t) * 150 + n];
      } else if (r < 17) {
        int q = r - 9;
        for (int t = 0; t < 20; ++t) v += ge[q * 20 + t] * W1[(3680 + t) * 150 + n];
      } else {
        int q = r - 17;
        for (int t = 0; t < 20; ++t) v += se[q * 20 + t] * W1[(3700 + t) * 150 + n];
      }
    }
    projs[idx] = v;
  }
}

// ---------------------------------------------------------------------------
// convert: g (fp32 [N][GI]) -> gpad (bf16 [N][KP], zero-padded). Coalesced.
// ---------------------------------------------------------------------------
__global__ __launch_bounds__(256)
void convert_kernel(const float* __restrict__ g, unsigned short* __restrict__ gpad, int N) {
  int idx = blockIdx.x * 256 + threadIdx.x;
  int total = N * (KP / 8);
  if (idx >= total) return;
  int row = idx / (KP / 8);
  int u   = idx - row * (KP / 8);
  int k0  = u * 8;
  u32x4 o; o.x = 0u; o.y = 0u; o.z = 0u; o.w = 0u;
  const float* gr = g + (long)row * GI;
  if (k0 + 4 <= GI) { f32x4 a = *(const f32x4*)(gr + k0);     o.x = pk2(a.x, a.y); o.y = pk2(a.z, a.w); }
  if (k0 + 8 <= GI) { f32x4 b = *(const f32x4*)(gr + k0 + 4); o.z = pk2(b.x, b.y); o.w = pk2(b.z, b.w); }
  *(u32x4*)(gpad + (long)row * KP + k0) = o;
}

// ---------------------------------------------------------------------------
// ab v2: AB[m] = [(G@W1a)[m] | (G@W1b)[m]] bf16.
// Double-buffered LDS (1 barrier/chunk), XOR-swizzled unpadded stage (no
// bank conflicts), bf16 source (gpad) when available.
// ---------------------------------------------------------------------------
template <bool PADG>
__global__ __launch_bounds__(256, 3)
void ab_kernel(const float* __restrict__ g, const unsigned short* __restrict__ gpad,
               const unsigned short* __restrict__ W1ab_t,
               unsigned short* __restrict__ AB, int N) {
  __shared__ __attribute__((aligned(16))) unsigned short sX[2][8192];  // 2 x 16KB
  const int t = threadIdx.x;
  const int m0 = blockIdx.x * 64;
  const int w = t >> 6, lane = t & 63, quad = lane >> 4, lm = lane & 15;
  const int cb = (t & 15) ^ (t >> 4);   // XOR-swizzled 16B-unit column

  f32x4 acc[4][5];
#pragma unroll
  for (int a = 0; a < 4; ++a)
#pragma unroll
    for (int b = 0; b < 5; ++b) { acc[a][b].x = 0.f; acc[a][b].y = 0.f; acc[a][b].z = 0.f; acc[a][b].w = 0.f; }

  u32x4 stg[4];
  auto fetch = [&](int c, u32x4 st[4]) {
#pragma unroll
    for (int j = 0; j < 4; ++j) {
      int row = m0 + j * 16 + (t >> 4); if (row >= N) row = N - 1;
      int k = c * BK + cb * 8;
      if constexpr (PADG) {
        st[j] = *(const u32x4*)(gpad + (long)row * KP + k);
      } else {
        u32x4 o; o.x = 0u; o.y = 0u; o.z = 0u; o.w = 0u;
        const float* gr = g + (long)row * GI + k;
        if (k + 4 <= GI) { f32x4 a = *(const f32x4*)gr;       o.x = pk2(a.x, a.y); o.y = pk2(a.z, a.w); }
        if (k + 8 <= GI) { f32x4 b = *(const f32x4*)(gr + 4); o.z = pk2(b.x, b.y); o.w = pk2(b.z, b.w); }
        st[j] = o;
      }
    }
  };

  fetch(0, stg);
  for (int c = 0; c < NCH; ++c) {
    unsigned short* buf = sX[c & 1];
#pragma unroll
    for (int j = 0; j < 4; ++j)
      *(u32x4*)(buf + (j * 256 + t) * 8) = stg[j];
    if (c + 1 < NCH) fetch(c + 1, stg);
    __syncthreads();
#pragma unroll
    for (int kk = 0; kk < 4; ++kk) {
      bf16x8 af[4];
#pragma unroll
      for (int mi = 0; mi < 4; ++mi) {
        int row = mi * 16 + lm;
        af[mi] = __builtin_bit_cast(bf16x8, *(const u32x4*)(buf + row * 128 + (((kk * 4 + quad) ^ lm) * 8)));
      }
#pragma unroll
      for (int tl = 0; tl < 5; ++tl) {
        int n = (w * 5 + tl) * 16 + lm;
        bf16x8 bfr = __builtin_bit_cast(bf16x8, *(const u32x4*)(W1ab_t + (long)n * KP + c * BK + kk * 32 + quad * 8));
#pragma unroll
        for (int mi = 0; mi < 4; ++mi)
          acc[mi][tl] = __builtin_amdgcn_mfma_f32_16x16x32_bf16(af[mi], bfr, acc[mi][tl], 0, 0, 0);
      }
    }
  }
#pragma unroll
  for (int mi = 0; mi < 4; ++mi)
#pragma unroll
    for (int reg = 0; reg < 4; ++reg) {
      int m = m0 + mi * 16 + quad * 4 + reg;
      if (m < N) {
#pragma unroll
        for (int tl = 0; tl < 5; ++tl) {
          int n = (w * 5 + tl) * 16 + lm;
          AB[(long)m * ABW + n] = f2bf(acc[mi][tl][reg]);
        }
      }
    }
}

// ---------------------------------------------------------------------------
// pair v2: BARRIER-FREE. wave = 16 pairs, everything wave-private:
// indices via shfl, product staging in private LDS slice [16][200],
// bias/h1/h2 in the same slice, layer3 shuffle-reduce. No __syncthreads.
// ---------------------------------------------------------------------------
template <bool PADG>
__global__ __launch_bounds__(256, 4)
void pair_kernel(const float* __restrict__ g, const unsigned short* __restrict__ gpad,
                 const float* __restrict__ msc,
                 const unsigned short* __restrict__ AB,
                 const unsigned short* __restrict__ W1c_t,
                 const unsigned short* __restrict__ W2_t,
                 const float* __restrict__ projs,
                 const float* __restrict__ b2, const float* __restrict__ W3,
                 const float* __restrict__ b3,
                 const int* __restrict__ mid, const int* __restrict__ aid,
                 const int* __restrict__ did, const int* __restrict__ gid,
                 const int* __restrict__ sid,
                 float* __restrict__ out, int P) {
  __shared__ __attribute__((aligned(16))) unsigned short sW[4][16 * 200];  // 25.6 KB
  const int t = threadIdx.x;
  const int w = t >> 6, lane = t & 63, quad = lane >> 4, lm = lane & 15;
  unsigned short* sWw = sW[w];

  const int pw0 = blockIdx.x * 64 + w * 16;

  // ---- per-wave index load (lanes 0..15) + broadcast via shfl
  int mv = 0, av = 0, dv = 0;
  float scv = 0.f;
  if (lane < 16) {
    int p = pw0 + lane; if (p >= P) p = P - 1;
    mv = mid[p]; av = aid[p];
    dv = did[p] | (gid[p] << 4) | (sid[p] << 8);
    scv = msc[mv] + msc[av];
  }
  const int mi_ = __shfl(mv, lm);
  const int ai_ = __shfl(av, lm);
  const int dgs = __shfl(dv, lm);

  const int rr = lane & 15;      // staging: this lane's pair row
  const int colq = lane >> 4;    // staging: this lane's 32-col quarter

  // ---- layer 1 bilinear, K = 1280, barrier-free with fetch-ahead
  f32x4 acc[12];
#pragma unroll
  for (int i = 0; i < 12; ++i) { acc[i].x = 0.f; acc[i].y = 0.f; acc[i].z = 0.f; acc[i].w = 0.f; }

  if constexpr (PADG) {
    const unsigned short* gmr = gpad + (long)mi_ * KP;
    const unsigned short* gar = gpad + (long)ai_ * KP;
    u32x4 xr[2], yr[2];
    auto fetch = [&](int c) {
      int k = c * BK + colq * 32;
      xr[0] = *(const u32x4*)(gmr + k);     xr[1] = *(const u32x4*)(gmr + k + 8);
      yr[0] = *(const u32x4*)(gar + k);     yr[1] = *(const u32x4*)(gar + k + 8);
    };
    u32x4 xr2[2], yr2[2];
    auto fetch2 = [&](int c) {
      int k = c * BK + colq * 32;
      xr2[0] = *(const u32x4*)(gmr + k + 16); xr2[1] = *(const u32x4*)(gmr + k + 24);
      yr2[0] = *(const u32x4*)(gar + k + 16); yr2[1] = *(const u32x4*)(gar + k + 24);
    };
    fetch(0); fetch2(0);
    for (int c = 0; c < NCH; ++c) {
      // products -> private LDS slice
#pragma unroll
      for (int h = 0; h < 2; ++h) {
        u32x4 o;
        o.x = mulbf2(xr[h].x, yr[h].x); o.y = mulbf2(xr[h].y, yr[h].y);
        o.z = mulbf2(xr[h].z, yr[h].z); o.w = mulbf2(xr[h].w, yr[h].w);
        *(u32x4*)&sWw[rr * 200 + colq * 32 + h * 8] = o;
      }
#pragma unroll
      for (int h = 0; h < 2; ++h) {
        u32x4 o;
        o.x = mulbf2(xr2[h].x, yr2[h].x); o.y = mulbf2(xr2[h].y, yr2[h].y);
        o.z = mulbf2(xr2[h].z, yr2[h].z); o.w = mulbf2(xr2[h].w, yr2[h].w);
        *(u32x4*)&sWw[rr * 200 + colq * 32 + 16 + h * 8] = o;
      }
      if (c + 1 < NCH) { fetch(c + 1); fetch2(c + 1); }
      // MFMA on chunk c (in-order DS pipe: writes above are visible)
#pragma unroll
      for (int kk = 0; kk < 4; ++kk) {
        bf16x8 af = __builtin_bit_cast(bf16x8, *(const u32x4*)&sWw[lm * 200 + kk * 32 + quad * 8]);
#pragma unroll
        for (int tl = 0; tl < 12; ++tl) {
          int n = tl * 16 + lm;
          bf16x8 bfr = __builtin_bit_cast(bf16x8, *(const u32x4*)(W1c_t + (long)n * KP + c * BK + kk * 32 + quad * 8));
          acc[tl] = __builtin_amdgcn_mfma_f32_16x16x32_bf16(af, bfr, acc[tl], 0, 0, 0);
        }
      }
    }
  } else {
    const float* gmr = g + (long)mi_ * GI;
    const float* gar = g + (long)ai_ * GI;
    for (int c = 0; c < NCH; ++c) {
#pragma unroll
      for (int h = 0; h < 4; ++h) {
        int k = c * BK + colq * 32 + h * 8;
        u32x4 o; o.x = 0u; o.y = 0u; o.z = 0u; o.w = 0u;
        if (k + 4 <= GI) {
          f32x4 x = *(const f32x4*)(gmr + k);
          f32x4 y = *(const f32x4*)(gar + k);
          o.x = pk2(x.x * y.x, x.y * y.y); o.y = pk2(x.z * y.z, x.w * y.w);
        }
        if (k + 8 <= GI) {
          f32x4 x = *(const f32x4*)(gmr + k + 4);
          f32x4 y = *(const f32x4*)(gar + k + 4);
          o.z = pk2(x.x * y.x, x.y * y.y); o.w = pk2(x.z * y.z, x.w * y.w);
        }
        *(u32x4*)&sWw[rr * 200 + colq * 32 + h * 8] = o;
      }
#pragma unroll
      for (int kk = 0; kk < 4; ++kk) {
        bf16x8 af = __builtin_bit_cast(bf16x8, *(const u32x4*)&sWw[lm * 200 + kk * 32 + quad * 8]);
#pragma unroll
        for (int tl = 0; tl < 12; ++tl) {
          int n = tl * 16 + lm;
          bf16x8 bfr = __builtin_bit_cast(bf16x8, *(const u32x4*)(W1c_t + (long)n * KP + c * BK + kk * 32 + quad * 8));
          acc[tl] = __builtin_amdgcn_mfma_f32_16x16x32_bf16(af, bfr, acc[tl], 0, 0, 0);
        }
      }
    }
  }

  // ---- bias tile into sWw (stride 200): AB[mid] + AB[aid](B half) + projs
  {
    const unsigned short* Ar = AB + (long)mi_ * ABW;
    const unsigned short* Br = AB + (long)ai_ * ABW + 160;
    const float* dp = projs + (dgs & 15) * NP;
    const float* gp = projs + (9 + ((dgs >> 4) & 15)) * NP;
    const float* sp = projs + (17 + (dgs >> 8)) * NP;
#pragma unroll
    for (int jj = 0; jj < 6; ++jj) {
      int n = colq * 48 + jj * 8;
      f32x4 p0v = *(const f32x4*)(dp + n)     + *(const f32x4*)(gp + n)     + *(const f32x4*)(sp + n);
      f32x4 p1v = *(const f32x4*)(dp + n + 4) + *(const f32x4*)(gp + n + 4) + *(const f32x4*)(sp + n + 4);
      if (n + 8 <= 160) {
        u32x4 a8 = *(const u32x4*)(Ar + n);
        u32x4 b8 = *(const u32x4*)(Br + n);
        p0v.x += bf2f(a8.x & 0xffff) + bf2f(b8.x & 0xffff);
        p0v.y += bf2f(a8.x >> 16)    + bf2f(b8.x >> 16);
        p0v.z += bf2f(a8.y & 0xffff) + bf2f(b8.y & 0xffff);
        p0v.w += bf2f(a8.y >> 16)    + bf2f(b8.y >> 16);
        p1v.x += bf2f(a8.z & 0xffff) + bf2f(b8.z & 0xffff);
        p1v.y += bf2f(a8.z >> 16)    + bf2f(b8.z >> 16);
        p1v.z += bf2f(a8.w & 0xffff) + bf2f(b8.w & 0xffff);
        p1v.w += bf2f(a8.w >> 16)    + bf2f(b8.w >> 16);
      }
      u32x4 o;
      o.x = pk2(p0v.x, p0v.y); o.y = pk2(p0v.z, p0v.w);
      o.z = pk2(p1v.x, p1v.y); o.w = pk2(p1v.z, p1v.w);
      *(u32x4*)&sWw[rr * 200 + n] = o;
    }
  }

  // ---- epilogue 1: h1 = relu(acc + bias) in-place (cell owner = this lane)
#pragma unroll
  for (int tl = 0; tl < 12; ++tl) {
    int n = tl * 16 + lm;
#pragma unroll
    for (int reg = 0; reg < 4; ++reg) {
      int m = quad * 4 + reg;
      float v = acc[tl][reg] + bf2f(sWw[m * 200 + n]);
      sWw[m * 200 + n] = f2bf(fmaxf(v, 0.f));
    }
  }

  // ---- layer 2: h1[16][192] @ W2_t  (wave-private)
  f32x4 acc2[12];
#pragma unroll
  for (int i = 0; i < 12; ++i) { acc2[i].x = 0.f; acc2[i].y = 0.f; acc2[i].z = 0.f; acc2[i].w = 0.f; }
#pragma unroll
  for (int kk = 0; kk < 6; ++kk) {
    bf16x8 af = __builtin_bit_cast(bf16x8, *(const u32x4*)&sWw[lm * 200 + kk * 32 + quad * 8]);
#pragma unroll
    for (int tl = 0; tl < 12; ++tl) {
      int n = tl * 16 + lm;
      bf16x8 bfr = __builtin_bit_cast(bf16x8, *(const u32x4*)(W2_t + n * NP + kk * 32 + quad * 8));
      acc2[tl] = __builtin_amdgcn_mfma_f32_16x16x32_bf16(af, bfr, acc2[tl], 0, 0, 0);
    }
  }

  // ---- epilogue 2: h2 = relu(acc2 + b2)
#pragma unroll
  for (int tl = 0; tl < 12; ++tl) {
    int n = tl * 16 + lm;
    float bb = (n < 150) ? b2[n] : 0.f;
#pragma unroll
    for (int reg = 0; reg < 4; ++reg) {
      int m = quad * 4 + reg;
      float v = acc2[tl][reg] + bb;
      sWw[m * 200 + n] = f2bf(fmaxf(v, 0.f));
    }
  }

  // ---- layer 3: pairwise = h2 . W3 ; shuffle-reduce over col quarters
  {
    float sum = 0.f;
#pragma unroll
    for (int jj = 0; jj < 6; ++jj) {
      int n = colq * 48 + jj * 8;
      u32x4 hv = *(const u32x4*)&sWw[rr * 200 + n];
      const unsigned int* hw = (const unsigned int*)&hv;
#pragma unroll
      for (int e = 0; e < 4; ++e) {
        int nn = n + e * 2;
        if (nn < 150)     sum += bf2f(hw[e] & 0xffff) * W3[nn];
        if (nn + 1 < 150) sum += bf2f(hw[e] >> 16)    * W3[nn + 1];
      }
    }
    sum += __shfl_xor(sum, 16);
    sum += __shfl_xor(sum, 32);
    if (lane < 16) {
      int p = pw0 + lane;
      if (p < P) out[p] = scv + sum + b3[0];
    }
  }
}

extern "C" void kernel_launch(void* const* d_in, const int* in_sizes, int n_in,
                              void* d_out, int out_size, void* d_ws, size_t ws_size,
                              hipStream_t stream) {
  (void)n_in; (void)out_size;
  const float* g   = (const float*)d_in[0];
  const float* msc = (const float*)d_in[1];
  const float* de  = (const float*)d_in[2];
  const float* ge  = (const float*)d_in[3];
  const float* se  = (const float*)d_in[4];
  const float* W1  = (const float*)d_in[5];
  const float* b1  = (const float*)d_in[6];
  const float* W2  = (const float*)d_in[7];
  const float* b2  = (const float*)d_in[8];
  const float* W3  = (const float*)d_in[9];
  const float* b3  = (const float*)d_in[10];
  const int* mid = (const int*)d_in[11];
  const int* aid = (const int*)d_in[12];
  const int* did = (const int*)d_in[13];
  const int* gid = (const int*)d_in[14];
  const int* sid = (const int*)d_in[15];
  const int N = in_sizes[0] / GI;
  const int P = in_sizes[11];
  float* out = (float*)d_out;

  char* ws = (char*)d_ws;
  size_t off = 0;
  auto alloc = [&](size_t bytes) { char* p = ws + off; off = (off + bytes + 255) & ~(size_t)255; return p; };
  unsigned short* AB     = (unsigned short*)alloc((size_t)N * ABW * 2);
  unsigned short* W1ab_t = (unsigned short*)alloc((size_t)ABW * KP * 2);
  unsigned short* W1c_t  = (unsigned short*)alloc((size_t)NP * KP * 2);
  unsigned short* W2_t   = (unsigned short*)alloc((size_t)NP * NP * 2);
  float* projs           = (float*)alloc((size_t)20 * NP * 4);

  size_t gpad_bytes = (size_t)N * KP * 2;
  unsigned short* gpad = nullptr;
  if (off + gpad_bytes + 256 <= ws_size)
    gpad = (unsigned short*)alloc(gpad_bytes);

  const int prep_total = ABW * KP + NP * KP + NP * NP + 20 * NP;
  prep_kernel<<<(prep_total + 255) / 256, 256, 0, stream>>>(W1, W2, b1, de, ge, se,
                                                            W1ab_t, W1c_t, W2_t, projs);
  if (gpad) {
    int cv_total = N * (KP / 8);
    convert_kernel<<<(cv_total + 255) / 256, 256, 0, stream>>>(g, gpad, N);
    ab_kernel<true><<<(N + 63) / 64, 256, 0, stream>>>(g, gpad, W1ab_t, AB, N);
    pair_kernel<true><<<(P + 63) / 64, 256, 0, stream>>>(g, gpad, msc, AB, W1c_t, W2_t, projs,
                                                         b2, W3, b3, mid, aid, did, gid, sid, out, P);
  } else {
    ab_kernel<false><<<(N + 63) / 64, 256, 0, stream>>>(g, gpad, W1ab_t, AB, N);
    pair_kernel<false><<<(P + 63) / 64, 256, 0, stream>>>(g, gpad, msc, AB, W1c_t, W2_t, projs,
                                                          b2, W3, b3, mid, aid, did, gid, sid, out, P);
  }
}

// Round 4
// 943.295 us; speedup vs baseline: 1.2699x; 1.2699x over previous
//
#include <hip/hip_runtime.h>

#define GI  1220          // g_i feature dim
#define KP  1280          // K padded to 40 * 32
#define NP  192           // hidden dim padded 150 -> 192
#define ABW 320           // AB row: A[0:160) | B[160:320)

typedef __bf16        bf16x8 __attribute__((ext_vector_type(8)));
typedef float         f32x4  __attribute__((ext_vector_type(4)));
typedef unsigned int  u32x4  __attribute__((ext_vector_type(4)));

__device__ __forceinline__ unsigned short f2bf(float f) {
  __bf16 h = (__bf16)f;
  return __builtin_bit_cast(unsigned short, h);
}
__device__ __forceinline__ float bf2f(unsigned short u) {
  return (float)__builtin_bit_cast(__bf16, u);
}
__device__ __forceinline__ unsigned int pk2(float a, float b) {
  return (unsigned int)f2bf(a) | ((unsigned int)f2bf(b) << 16);
}
__device__ __forceinline__ unsigned int mulbf2(unsigned int a, unsigned int b) {
  float xl = __builtin_bit_cast(float, a << 16);
  float xh = __builtin_bit_cast(float, a & 0xffff0000u);
  float yl = __builtin_bit_cast(float, b << 16);
  float yh = __builtin_bit_cast(float, b & 0xffff0000u);
  return pk2(xl * yl, xh * yh);
}

// ---------------------------------------------------------------------------
// prep: bf16 transposed weights + fp32 proj tables (b1 folded into dist rows)
// ---------------------------------------------------------------------------
__global__ void prep_kernel(const float* __restrict__ W1, const float* __restrict__ W2,
                            const float* __restrict__ b1,
                            const float* __restrict__ de, const float* __restrict__ ge,
                            const float* __restrict__ se,
                            unsigned short* __restrict__ W1ab_t,
                            unsigned short* __restrict__ W1c_t,
                            unsigned short* __restrict__ W2_t,
                            float* __restrict__ projs) {
  int idx = blockIdx.x * 256 + threadIdx.x;
  const int R1 = ABW * KP, R2 = NP * KP, R3 = NP * NP, R4 = 20 * NP;
  if (idx < R1) {
    int n = idx / KP, k = idx % KP;
    float v = 0.f;
    if (k < GI) {
      if (n < 150)                  v = W1[k * 150 + n];
      else if (n >= 160 && n < 310) v = W1[(GI + k) * 150 + (n - 160)];
    }
    W1ab_t[idx] = f2bf(v);
    return;
  }
  idx -= R1;
  if (idx < R2) {
    int n = idx / KP, k = idx % KP;
    float v = (k < GI && n < 150) ? W1[(2 * GI + k) * 150 + n] : 0.f;
    W1c_t[idx] = f2bf(v);
    return;
  }
  idx -= R2;
  if (idx < R3) {
    int n = idx / NP, k = idx % NP;
    float v = (n < 150 && k < 150) ? W2[k * 150 + n] : 0.f;
    W2_t[idx] = f2bf(v);
    return;
  }
  idx -= R3;
  if (idx < R4) {
    int r = idx / NP, n = idx % NP;
    float v = 0.f;
    if (n < 150) {
      if (r < 9) {
        v = b1[n];
        for (int t = 0; t < 20; ++t) v += de[r * 20 + t] * W1[(3660 + t) * 150 + n];
      } else if (r < 17) {
        int q = r - 9;
        for (int t = 0; t < 20; ++t) v += ge[q * 20 + t] * W1[(3680 + t) * 150 + n];
      } else {
        int q = r - 17;
        for (int t = 0; t < 20; ++t) v += se[q * 20 + t] * W1[(3700 + t) * 150 + n];
      }
    }
    projs[idx] = v;
  }
}

// ---------------------------------------------------------------------------
// convert: g (fp32 [N][GI]) -> gpad (bf16 [N][KP], zero-padded). Coalesced.
// ---------------------------------------------------------------------------
__global__ __launch_bounds__(256)
void convert_kernel(const float* __restrict__ g, unsigned short* __restrict__ gpad, int N) {
  int idx = blockIdx.x * 256 + threadIdx.x;
  int total = N * (KP / 8);
  if (idx >= total) return;
  int row = idx / (KP / 8);
  int u   = idx - row * (KP / 8);
  int k0  = u * 8;
  u32x4 o; o.x = 0u; o.y = 0u; o.z = 0u; o.w = 0u;
  const float* gr = g + (long)row * GI;
  if (k0 + 4 <= GI) { f32x4 a = *(const f32x4*)(gr + k0);     o.x = pk2(a.x, a.y); o.y = pk2(a.z, a.w); }
  if (k0 + 8 <= GI) { f32x4 b = *(const f32x4*)(gr + k0 + 4); o.z = pk2(b.x, b.y); o.w = pk2(b.z, b.w); }
  *(u32x4*)(gpad + (long)row * KP + k0) = o;
}

// ---------------------------------------------------------------------------
// ab v3: barrier-free, LDS-free. Each lane loads its A-fragment (16B of a
// gpad row) directly from global; 4 quads of a row share one 64B line (L1).
// Wave w: all 4 msubs x ntl [w*5, w*5+5).
// ---------------------------------------------------------------------------
template <bool PADG>
__global__ __launch_bounds__(256, 4)
void ab_kernel(const float* __restrict__ g, const unsigned short* __restrict__ gpad,
               const unsigned short* __restrict__ W1ab_t,
               unsigned short* __restrict__ AB, int N) {
  const int t = threadIdx.x;
  const int m0 = blockIdx.x * 64;
  const int w = t >> 6, lane = t & 63, quad = lane >> 4, lm = lane & 15;

  const unsigned short* gp16[4];
  const float* gp32[4];
#pragma unroll
  for (int mi = 0; mi < 4; ++mi) {
    int row = m0 + mi * 16 + lm; if (row >= N) row = N - 1;
    if constexpr (PADG) gp16[mi] = gpad + (long)row * KP;
    else                gp32[mi] = g + (long)row * GI;
  }

  f32x4 acc[4][5];
#pragma unroll
  for (int a = 0; a < 4; ++a)
#pragma unroll
    for (int b = 0; b < 5; ++b) { acc[a][b].x = 0.f; acc[a][b].y = 0.f; acc[a][b].z = 0.f; acc[a][b].w = 0.f; }

  for (int i = 0; i < 40; ++i) {
    int ko = i * 32 + quad * 8;
    bf16x8 af[4];
#pragma unroll
    for (int mi = 0; mi < 4; ++mi) {
      if constexpr (PADG) {
        af[mi] = __builtin_bit_cast(bf16x8, *(const u32x4*)(gp16[mi] + ko));
      } else {
        f32x4 a0, a1;
        a0.x=0;a0.y=0;a0.z=0;a0.w=0; a1=a0;
        if (ko + 4 <= GI) a0 = *(const f32x4*)(gp32[mi] + ko);
        if (ko + 8 <= GI) a1 = *(const f32x4*)(gp32[mi] + ko + 4);
        u32x4 o; o.x = pk2(a0.x, a0.y); o.y = pk2(a0.z, a0.w);
        o.z = pk2(a1.x, a1.y); o.w = pk2(a1.z, a1.w);
        af[mi] = __builtin_bit_cast(bf16x8, o);
      }
    }
#pragma unroll
    for (int tl = 0; tl < 5; ++tl) {
      int n = (w * 5 + tl) * 16 + lm;
      bf16x8 bfr = __builtin_bit_cast(bf16x8, *(const u32x4*)(W1ab_t + (long)n * KP + ko));
#pragma unroll
      for (int mi = 0; mi < 4; ++mi)
        acc[mi][tl] = __builtin_amdgcn_mfma_f32_16x16x32_bf16(af[mi], bfr, acc[mi][tl], 0, 0, 0);
    }
  }
#pragma unroll
  for (int mi = 0; mi < 4; ++mi)
#pragma unroll
    for (int reg = 0; reg < 4; ++reg) {
      int m = m0 + mi * 16 + quad * 4 + reg;
      if (m < N) {
#pragma unroll
        for (int tl = 0; tl < 5; ++tl) {
          int n = (w * 5 + tl) * 16 + lm;
          AB[(long)m * ABW + n] = f2bf(acc[mi][tl][reg]);
        }
      }
    }
}

// ---------------------------------------------------------------------------
// pair v4: barrier-free K-loop, direct per-lane gather of A-fragments from
// gpad + in-register product. Wave (wm,wn): rows [32wm,32wm+32) x ntl
// [wn*6, wn*6+6) — B-frags amortized over 2 msubs, A redundancy 2x (L1-hot).
// Epilogue: in-place bias/h1/h2 in one 25.6KB LDS region, 5 barriers total.
// ---------------------------------------------------------------------------
template <bool PADG>
__global__ __launch_bounds__(256, 4)
void pair_kernel(const float* __restrict__ g, const unsigned short* __restrict__ gpad,
                 const float* __restrict__ msc,
                 const unsigned short* __restrict__ AB,
                 const unsigned short* __restrict__ W1c_t,
                 const unsigned short* __restrict__ W2_t,
                 const float* __restrict__ projs,
                 const float* __restrict__ b2, const float* __restrict__ W3,
                 const float* __restrict__ b3,
                 const int* __restrict__ mid, const int* __restrict__ aid,
                 const int* __restrict__ did, const int* __restrict__ gid,
                 const int* __restrict__ sid,
                 float* __restrict__ out, int P) {
  __shared__ __attribute__((aligned(16))) unsigned short sH[64 * 200];  // bias -> h1 -> h2
  __shared__ int sM[64], sA[64], sDGS[64];

  const int t = threadIdx.x;
  const int p0 = blockIdx.x * 64;
  const int w = t >> 6, lane = t & 63, quad = lane >> 4, lm = lane & 15;
  const int wm = w >> 1, wn = w & 1;

  if (t < 64) {
    int p = p0 + t; if (p >= P) p = P - 1;
    sM[t] = mid[p]; sA[t] = aid[p];
    sDGS[t] = did[p] | (gid[p] << 4) | (sid[p] << 8);
  }
  __syncthreads();

  // per-lane row pointers for its 2 msubs (rows 32*wm + mi*16 + lm)
  const int r0 = wm * 32 + lm;
  const unsigned short* gmp[2]; const unsigned short* gap[2];
  const float* gmp32[2]; const float* gap32[2];
#pragma unroll
  for (int mi = 0; mi < 2; ++mi) {
    int rr = r0 + mi * 16;
    if constexpr (PADG) {
      gmp[mi] = gpad + (long)sM[rr] * KP;
      gap[mi] = gpad + (long)sA[rr] * KP;
    } else {
      gmp32[mi] = g + (long)sM[rr] * GI;
      gap32[mi] = g + (long)sA[rr] * GI;
    }
  }

  // ---- bias tile into sH (stride 200): AB[mid] + AB[aid](B half) + projs
  {
    const int r = t >> 2, s = t & 3;
    const unsigned short* Ar = AB + (long)sM[r] * ABW;
    const unsigned short* Br = AB + (long)sA[r] * ABW + 160;
    int dgs = sDGS[r];
    const float* dp = projs + (dgs & 15) * NP;
    const float* gp = projs + (9 + ((dgs >> 4) & 15)) * NP;
    const float* sp = projs + (17 + (dgs >> 8)) * NP;
#pragma unroll
    for (int jj = 0; jj < 6; ++jj) {
      int n = s * 48 + jj * 8;
      f32x4 p0v = *(const f32x4*)(dp + n)     + *(const f32x4*)(gp + n)     + *(const f32x4*)(sp + n);
      f32x4 p1v = *(const f32x4*)(dp + n + 4) + *(const f32x4*)(gp + n + 4) + *(const f32x4*)(sp + n + 4);
      if (n + 8 <= 160) {
        u32x4 a8 = *(const u32x4*)(Ar + n);
        u32x4 b8 = *(const u32x4*)(Br + n);
        p0v.x += bf2f(a8.x & 0xffff) + bf2f(b8.x & 0xffff);
        p0v.y += bf2f(a8.x >> 16)    + bf2f(b8.x >> 16);
        p0v.z += bf2f(a8.y & 0xffff) + bf2f(b8.y & 0xffff);
        p0v.w += bf2f(a8.y >> 16)    + bf2f(b8.y >> 16);
        p1v.x += bf2f(a8.z & 0xffff) + bf2f(b8.z & 0xffff);
        p1v.y += bf2f(a8.z >> 16)    + bf2f(b8.z >> 16);
        p1v.z += bf2f(a8.w & 0xffff) + bf2f(b8.w & 0xffff);
        p1v.w += bf2f(a8.w >> 16)    + bf2f(b8.w >> 16);
      }
      u32x4 o;
      o.x = pk2(p0v.x, p0v.y); o.y = pk2(p0v.z, p0v.w);
      o.z = pk2(p1v.x, p1v.y); o.w = pk2(p1v.z, p1v.w);
      *(u32x4*)&sH[r * 200 + n] = o;
    }
  }

  // ---- layer 1 bilinear: barrier-free direct-gather K-loop, 1-step prefetch
  f32x4 acc[2][6];
#pragma unroll
  for (int a = 0; a < 2; ++a)
#pragma unroll
    for (int b = 0; b < 6; ++b) { acc[a][b].x = 0.f; acc[a][b].y = 0.f; acc[a][b].z = 0.f; acc[a][b].w = 0.f; }

  if constexpr (PADG) {
    u32x4 cxa[2], cxb[2];
#pragma unroll
    for (int mi = 0; mi < 2; ++mi) {
      cxa[mi] = *(const u32x4*)(gmp[mi] + quad * 8);
      cxb[mi] = *(const u32x4*)(gap[mi] + quad * 8);
    }
    for (int i = 0; i < 40; ++i) {
      u32x4 nxa[2], nxb[2];
      if (i + 1 < 40) {
        int ko2 = (i + 1) * 32 + quad * 8;
#pragma unroll
        for (int mi = 0; mi < 2; ++mi) {
          nxa[mi] = *(const u32x4*)(gmp[mi] + ko2);
          nxb[mi] = *(const u32x4*)(gap[mi] + ko2);
        }
      }
      bf16x8 af[2];
#pragma unroll
      for (int mi = 0; mi < 2; ++mi) {
        u32x4 o;
        o.x = mulbf2(cxa[mi].x, cxb[mi].x); o.y = mulbf2(cxa[mi].y, cxb[mi].y);
        o.z = mulbf2(cxa[mi].z, cxb[mi].z); o.w = mulbf2(cxa[mi].w, cxb[mi].w);
        af[mi] = __builtin_bit_cast(bf16x8, o);
      }
      int ko = i * 32 + quad * 8;
#pragma unroll
      for (int tl = 0; tl < 6; ++tl) {
        int n = (wn * 6 + tl) * 16 + lm;
        bf16x8 bfr = __builtin_bit_cast(bf16x8, *(const u32x4*)(W1c_t + (long)n * KP + ko));
        acc[0][tl] = __builtin_amdgcn_mfma_f32_16x16x32_bf16(af[0], bfr, acc[0][tl], 0, 0, 0);
        acc[1][tl] = __builtin_amdgcn_mfma_f32_16x16x32_bf16(af[1], bfr, acc[1][tl], 0, 0, 0);
      }
#pragma unroll
      for (int mi = 0; mi < 2; ++mi) { cxa[mi] = nxa[mi]; cxb[mi] = nxb[mi]; }
    }
  } else {
    for (int i = 0; i < 40; ++i) {
      int ko = i * 32 + quad * 8;
      bf16x8 af[2];
#pragma unroll
      for (int mi = 0; mi < 2; ++mi) {
        f32x4 a0, a1, b0, b1;
        a0.x=0;a0.y=0;a0.z=0;a0.w=0; a1=a0; b0=a0; b1=a0;
        if (ko + 4 <= GI) { a0 = *(const f32x4*)(gmp32[mi] + ko);     b0 = *(const f32x4*)(gap32[mi] + ko); }
        if (ko + 8 <= GI) { a1 = *(const f32x4*)(gmp32[mi] + ko + 4); b1 = *(const f32x4*)(gap32[mi] + ko + 4); }
        u32x4 o;
        o.x = pk2(a0.x * b0.x, a0.y * b0.y); o.y = pk2(a0.z * b0.z, a0.w * b0.w);
        o.z = pk2(a1.x * b1.x, a1.y * b1.y); o.w = pk2(a1.z * b1.z, a1.w * b1.w);
        af[mi] = __builtin_bit_cast(bf16x8, o);
      }
#pragma unroll
      for (int tl = 0; tl < 6; ++tl) {
        int n = (wn * 6 + tl) * 16 + lm;
        bf16x8 bfr = __builtin_bit_cast(bf16x8, *(const u32x4*)(W1c_t + (long)n * KP + ko));
        acc[0][tl] = __builtin_amdgcn_mfma_f32_16x16x32_bf16(af[0], bfr, acc[0][tl], 0, 0, 0);
        acc[1][tl] = __builtin_amdgcn_mfma_f32_16x16x32_bf16(af[1], bfr, acc[1][tl], 0, 0, 0);
      }
    }
  }
  __syncthreads();   // bias fully written (and K-loop done)

  // ---- epilogue 1: h1 = relu(acc + bias) in-place
#pragma unroll
  for (int mi = 0; mi < 2; ++mi)
#pragma unroll
    for (int tl = 0; tl < 6; ++tl) {
      int n = (wn * 6 + tl) * 16 + lm;
#pragma unroll
      for (int reg = 0; reg < 4; ++reg) {
        int m = wm * 32 + mi * 16 + quad * 4 + reg;
        float v = acc[mi][tl][reg] + bf2f(sH[m * 200 + n]);
        sH[m * 200 + n] = f2bf(fmaxf(v, 0.f));
      }
    }
  __syncthreads();

  // ---- layer 2: h1[64][192] @ W2_t (A-frags from LDS)
  f32x4 acc2[2][6];
#pragma unroll
  for (int a = 0; a < 2; ++a)
#pragma unroll
    for (int b = 0; b < 6; ++b) { acc2[a][b].x = 0.f; acc2[a][b].y = 0.f; acc2[a][b].z = 0.f; acc2[a][b].w = 0.f; }
#pragma unroll
  for (int kk = 0; kk < 6; ++kk) {
    bf16x8 af[2];
#pragma unroll
    for (int mi = 0; mi < 2; ++mi)
      af[mi] = __builtin_bit_cast(bf16x8, *(const u32x4*)&sH[(wm * 32 + mi * 16 + lm) * 200 + kk * 32 + quad * 8]);
#pragma unroll
    for (int tl = 0; tl < 6; ++tl) {
      int n = (wn * 6 + tl) * 16 + lm;
      bf16x8 bfr = __builtin_bit_cast(bf16x8, *(const u32x4*)(W2_t + n * NP + kk * 32 + quad * 8));
      acc2[0][tl] = __builtin_amdgcn_mfma_f32_16x16x32_bf16(af[0], bfr, acc2[0][tl], 0, 0, 0);
      acc2[1][tl] = __builtin_amdgcn_mfma_f32_16x16x32_bf16(af[1], bfr, acc2[1][tl], 0, 0, 0);
    }
  }
  __syncthreads();   // everyone done reading h1

  // ---- epilogue 2: h2 = relu(acc2 + b2) -> same cells
#pragma unroll
  for (int mi = 0; mi < 2; ++mi)
#pragma unroll
    for (int tl = 0; tl < 6; ++tl) {
      int n = (wn * 6 + tl) * 16 + lm;
      float bb = (n < 150) ? b2[n] : 0.f;
#pragma unroll
      for (int reg = 0; reg < 4; ++reg) {
        int m = wm * 32 + mi * 16 + quad * 4 + reg;
        float v = acc2[mi][tl][reg] + bb;
        sH[m * 200 + n] = f2bf(fmaxf(v, 0.f));
      }
    }
  __syncthreads();

  // ---- layer 3: pairwise = h2 . W3 ; sij = ms_i + ms_j + pairwise + b3
  {
    const int r = t >> 2, s = t & 3;
    float sum = 0.f;
#pragma unroll
    for (int j = 0; j < 48; ++j) {
      int n = s * 48 + j;
      if (n < 150) sum += bf2f(sH[r * 200 + n]) * W3[n];
    }
    sum += __shfl_xor(sum, 1);
    sum += __shfl_xor(sum, 2);
    if (s == 0) {
      int p = p0 + r;
      if (p < P) out[p] = msc[sM[r]] + msc[sA[r]] + sum + b3[0];
    }
  }
}

extern "C" void kernel_launch(void* const* d_in, const int* in_sizes, int n_in,
                              void* d_out, int out_size, void* d_ws, size_t ws_size,
                              hipStream_t stream) {
  (void)n_in; (void)out_size;
  const float* g   = (const float*)d_in[0];
  const float* msc = (const float*)d_in[1];
  const float* de  = (const float*)d_in[2];
  const float* ge  = (const float*)d_in[3];
  const float* se  = (const float*)d_in[4];
  const float* W1  = (const float*)d_in[5];
  const float* b1  = (const float*)d_in[6];
  const float* W2  = (const float*)d_in[7];
  const float* b2  = (const float*)d_in[8];
  const float* W3  = (const float*)d_in[9];
  const float* b3  = (const float*)d_in[10];
  const int* mid = (const int*)d_in[11];
  const int* aid = (const int*)d_in[12];
  const int* did = (const int*)d_in[13];
  const int* gid = (const int*)d_in[14];
  const int* sid = (const int*)d_in[15];
  const int N = in_sizes[0] / GI;
  const int P = in_sizes[11];
  float* out = (float*)d_out;

  char* ws = (char*)d_ws;
  size_t off = 0;
  auto alloc = [&](size_t bytes) { char* p = ws + off; off = (off + bytes + 255) & ~(size_t)255; return p; };
  unsigned short* AB     = (unsigned short*)alloc((size_t)N * ABW * 2);
  unsigned short* W1ab_t = (unsigned short*)alloc((size_t)ABW * KP * 2);
  unsigned short* W1c_t  = (unsigned short*)alloc((size_t)NP * KP * 2);
  unsigned short* W2_t   = (unsigned short*)alloc((size_t)NP * NP * 2);
  float* projs           = (float*)alloc((size_t)20 * NP * 4);

  size_t gpad_bytes = (size_t)N * KP * 2;
  unsigned short* gpad = nullptr;
  if (off + gpad_bytes + 256 <= ws_size)
    gpad = (unsigned short*)alloc(gpad_bytes);

  const int prep_total = ABW * KP + NP * KP + NP * NP + 20 * NP;
  prep_kernel<<<(prep_total + 255) / 256, 256, 0, stream>>>(W1, W2, b1, de, ge, se,
                                                            W1ab_t, W1c_t, W2_t, projs);
  if (gpad) {
    int cv_total = N * (KP / 8);
    convert_kernel<<<(cv_total + 255) / 256, 256, 0, stream>>>(g, gpad, N);
    ab_kernel<true><<<(N + 63) / 64, 256, 0, stream>>>(g, gpad, W1ab_t, AB, N);
    pair_kernel<true><<<(P + 63) / 64, 256, 0, stream>>>(g, gpad, msc, AB, W1c_t, W2_t, projs,
                                                         b2, W3, b3, mid, aid, did, gid, sid, out, P);
  } else {
    ab_kernel<false><<<(N + 63) / 64, 256, 0, stream>>>(g, gpad, W1ab_t, AB, N);
    pair_kernel<false><<<(P + 63) / 64, 256, 0, stream>>>(g, gpad, msc, AB, W1c_t, W2_t, projs,
                                                          b2, W3, b3, mid, aid, did, gid, sid, out, P);
  }
}